// Round 11
// baseline (129.371 us; speedup 1.0000x reference)
//
#include <hip/hip_runtime.h>
#include <hip/hip_bf16.h>

#define FEAT   256
#define TROWS  16
#define TBYTES (TROWS * FEAT * 4)   // 16 KiB per x-tile

typedef __attribute__((ext_vector_type(8))) short  short8;
typedef __attribute__((ext_vector_type(4))) float  floatx4;

__device__ __forceinline__ short f2bf(float f) {
    __hip_bfloat16 h = __float2bfloat16(f);   // RTNE; pairs fuse to v_cvt_pk_bf16_f32
    return __builtin_bit_cast(short, h);
}

// Byte-offset swizzle within a 16-row tile: XOR bits 4..6 with row (=o>>10) &7.
// Involution, 16 B-granular. Applied to gload_lds SOURCE (dest linear) and
// to every LDS READ.
__device__ __forceinline__ unsigned swz(unsigned o) {
    return o ^ (((o >> 10) & 7u) << 4);
}

// R11: ZERO-BARRIER pipeline (isolating R6's block-rendezvous cost).
// Each wave owns a PRIVATE 2x16KiB LDS slice and stages its tile itself
// (16 global_load_lds dwordx4). The 4 waves of a block process the SAME
// tile (col-split: wave w -> cols [64w,64w+64)) but never synchronize —
// the 4x redundant reads of the tile coalesce in L2 (R1-proven: FETCH ~1x).
// Per-wave counted vmcnt only:
//   iter it: STAGE(buf^1, t+1)            // 16 loads, fire-and-forget
//            s_waitcnt vmcnt(20)          // own g(t) retired; newer
//                                         // st(t-1) 4 + g(t+1) 16 in flight
//            compute tile t from buf      // ds_read/cvt/MFMA/epilogue/store
// LDS 128 KiB -> 1 block/CU, 4 waves/CU. Compute ~1.1K cyc/tile vs HBM pace
// ~5K cyc/tile-round -> HBM-bound if issue never blocks.
__global__ __launch_bounds__(256, 1) void gdn_kernel(
    const float* __restrict__ x,
    const float* __restrict__ beta,
    const float* __restrict__ gamma,
    float* __restrict__ out,
    int batch)
{
    __shared__ char ldsx[4 * 2 * TBYTES];   // 128 KiB: 4 waves x 2 bufs x 16 KiB

    const int tid  = threadIdx.x;
    const int lane = tid & 63;
    const int wave = tid >> 6;          // 0..3 -> 64-col slice
    const int l15  = lane & 15;
    const int grp  = lane >> 4;
    const int colbase = wave * 64;

    char* myLds = ldsx + wave * (2 * TBYTES);   // private slice

    // ---- One-time: gamma fragments (A-operand of swapped MFMA), 128 regs.
    // k-hat map k = ks*32 + grp*8 + i, shared by both operands (HW-verified:
    // R7 passes with this exact swapped-MFMA layout).
    short8 Bf[4][8];
    #pragma unroll
    for (int nt = 0; nt < 4; ++nt) {
        const int col = colbase + nt * 16 + l15;
        #pragma unroll
        for (int ks = 0; ks < 8; ++ks) {
            const int k0 = ks * 32 + grp * 8;
            short8 b;
            #pragma unroll
            for (int i = 0; i < 8; ++i)
                b[i] = f2bf(gamma[(size_t)(k0 + i) * FEAT + col]);
            Bf[nt][ks] = b;
        }
    }

    // beta_c per (nt, r): out-cols colbase + nt*16 + grp*4 + r
    floatx4 bc4[4];
    #pragma unroll
    for (int nt = 0; nt < 4; ++nt) {
        floatx4 b = *(const floatx4*)(beta + colbase + nt * 16 + grp * 4);
        #pragma unroll
        for (int r = 0; r < 4; ++r) bc4[nt][r] = fmaxf(b[r], 1e-6f);
    }

    const int stride = gridDim.x;                 // 256
    const int iters  = (batch >> 4) / stride;     // 64 (exact)
    const int t0     = blockIdx.x;

    // Private stage of tile `t` into my slice, buffer `buf`: 16 x 1 KiB.
    // Dest LINEAR (wave-uniform base + lane*16); source pre-swizzled.
    auto STAGE = [&](int buf, int t) {
        const char* gb = (const char*)x + (size_t)t * TBYTES;
        char* lbase = myLds + buf * TBYTES;
        #pragma unroll
        for (int r = 0; r < 16; ++r) {
            const unsigned d = (unsigned)(lane * 16 + r * 1024);
            __builtin_amdgcn_global_load_lds(
                (const __attribute__((address_space(1))) void*)(gb + swz(d)),
                (__attribute__((address_space(3))) void*)(lbase + d),
                16, 0, 0);
        }
    };

    STAGE(0, t0);   // prologue

    const unsigned xv = (unsigned)((l15 & 7) << 4);
    const unsigned p0 = (unsigned)(l15 * 1024 + grp * 32);

    for (int it = 0; it < iters; ++it) {
        const int itn = (it + 1 < iters) ? it + 1 : it;   // tail: redundant
        STAGE((it + 1) & 1, t0 + itn * stride);           // prefetch t+1

        // Own tile-it loads retired; st(t-1) 4 + g(t+1) 16 stay in flight.
        if (it == 0) asm volatile("s_waitcnt vmcnt(16)" ::: "memory");
        else         asm volatile("s_waitcnt vmcnt(20)" ::: "memory");
        __builtin_amdgcn_sched_barrier(0);

        const char* lb = myLds + (it & 1) * TBYTES;

        // ---- x^2 fragments (MFMA B-operand): row l15, k = ks*32+grp*8+i.
        short8 Af[8];
        #pragma unroll
        for (int ks = 0; ks < 8; ++ks) {
            floatx4 v0 = *(const floatx4*)(lb + ((p0 + ks * 128)      ^ xv));
            floatx4 v1 = *(const floatx4*)(lb + ((p0 + ks * 128 + 16) ^ xv));
            short8 a;
            #pragma unroll
            for (int i = 0; i < 4; ++i) {
                a[i]     = f2bf(v0[i] * v0[i]);
                a[4 + i] = f2bf(v1[i] * v1[i]);
            }
            Af[ks] = a;
        }

        // ---- MFMA over K=256, swapped: D[out-col][x-row].
        // C/D: col(lane&15)=x-row, row(grp*4+r)=out-col (R7-verified).
        floatx4 acc[4] = {{0.f,0.f,0.f,0.f},{0.f,0.f,0.f,0.f},
                          {0.f,0.f,0.f,0.f},{0.f,0.f,0.f,0.f}};
        #pragma unroll
        for (int ks = 0; ks < 8; ++ks) {
            #pragma unroll
            for (int nt = 0; nt < 4; ++nt) {
                acc[nt] = __builtin_amdgcn_mfma_f32_16x16x32_bf16(
                    Bf[nt][ks], Af[ks], acc[nt], 0, 0, 0);
            }
        }

        // ---- Epilogue: y = x * rsqrt(acc + beta_c); x from private LDS,
        // 4x ds_read_b128 + 4x global_store_dwordx4.
        const int rb = (t0 + it * stride) << 4;
        float* orow = out + (size_t)(rb + l15) * FEAT + colbase + grp * 4;
        #pragma unroll
        for (int nt = 0; nt < 4; ++nt) {
            const unsigned eo = (unsigned)(l15 * 1024 + (colbase + nt * 16 + grp * 4) * 4);
            floatx4 xval = *(const floatx4*)(lb + (eo ^ xv));
            floatx4 y;
            #pragma unroll
            for (int r = 0; r < 4; ++r)
                y[r] = xval[r] * rsqrtf(acc[nt][r] + bc4[nt][r]);
            *(floatx4*)(orow + nt * 16) = y;
        }
        // no barriers, no drains: buffer hazards are wave-local and ordered
        // by the vmcnt wait (writes) / register consumption (reads).
    }
}

extern "C" void kernel_launch(void* const* d_in, const int* in_sizes, int n_in,
                              void* d_out, int out_size, void* d_ws, size_t ws_size,
                              hipStream_t stream) {
    const float* x     = (const float*)d_in[0];
    const float* beta  = (const float*)d_in[1];
    const float* gamma = (const float*)d_in[2];
    float* out = (float*)d_out;

    const int batch = in_sizes[0] / FEAT;   // 262144

    dim3 grid(256);     // 1 block/CU (128 KiB LDS), 64 tiles per block
    dim3 block(256);    // 4 waves, each fully independent (zero barriers)
    hipLaunchKernelGGL(gdn_kernel, grid, block, 0, stream,
                       x, beta, gamma, out, batch);
}